// Round 8
// baseline (312.046 us; speedup 1.0000x reference)
//
#include <hip/hip_runtime.h>
#include <math.h>

// FeatureWeightNet v8 (MI355X / gfx950)  B=2, C=64, H=512, W=640.
// Stencil: thread = 4px quad x 16 ch (2 full groups -> in-thread gsum,
//   no LDS, no barriers). Block = 256 thr = 64x16 px tile, one ch-quad.
//   Grid = 2560 = 640 tiles x 4 ch-quads, quad innermost in XCD-chunked
//   order (offset lines L2-shared across the 4 quads), then y (halo rows
//   L2-shared), then strip.
//   Inner loop: direct-f4 + shufflevector (even-shift trick: 3 aligned f4
//   per (ch,row) serve wide{-4,0,4} AND narrow{-2,0,2} taps for 4 px).
//   18 weight f4s loaded ONCE and pinned via asm "+v" (v7-proven fix for
//   the R5/R6 FETCH explosion: backend rematerialized the off loads).
//   __launch_bounds__(256,2): VGPR budget 256 -> no remat/spill pressure.
// Head: 8->16->8->1 MLP + sigmoid from gsum[B,8,H,W] (d_ws), acc fallback.

typedef float f4 __attribute__((ext_vector_type(4)));
#define EPSV 1e-5f

template<bool WRITE_GSUM>
__global__ __launch_bounds__(256, 2) void fwn_stencil(
    const float* __restrict__ F,    // [B,64,H,W]
    const float* __restrict__ off,  // [B,18,H,W]
    float* __restrict__ accp,       // [B,64,H,W]
    float* __restrict__ gsum,       // [B,8,H,W]
    int H, int W)
{
    const int HW = H * W;

    // 2560 blocks = 8 XCDs * 320. logical l: quad fastest, then y, then strip.
    const int f = blockIdx.x;
    const int l = (f & 7) * 320 + (f >> 3);
    const int quad  = l & 3;           // channel quad 0..3 (16 ch each)
    const int by    = (l >> 2) & 31;   // y tile (16 rows)
    const int strip = l >> 7;          // 0..19
    const int bx = strip % 10;         // x tile (64 px)
    const int b  = strip / 10;

    const int tid = threadIdx.x;
    const int qx = tid & 15;
    const int ry = tid >> 4;           // 0..15
    const int w = bx * 64 + qx * 4;
    const int h = by * 16 + ry;
    const int c0 = quad * 16;

    // reflected rows for dy = {-4,-2,0,2,4}
    int rowoff[5];
    #pragma unroll
    for (int k = 0; k < 5; ++k) {
        int hh = h + 2 * k - 4;
        if (hh < 0) hh = -hh;
        if (hh >= H) hh = 2 * H - 2 - hh;
        rowoff[k] = hh * W;
    }

    // 18 per-pixel weight f4s, pre-scaled 0.5, loaded once and PINNED.
    const float* op = off + (size_t)b * 18 * HW + h * W + w;
    f4 wb[9], wn[9];
    #pragma unroll
    for (int s = 0; s < 9; ++s) {
        wb[s] = 0.5f * *(const f4*)(op + (size_t)s * HW);
        wn[s] = 0.5f * *(const f4*)(op + (size_t)(s + 9) * HW);
    }
    #pragma unroll
    for (int s = 0; s < 9; ++s) {
        asm volatile("" : "+v"(wb[s]));
        asm volatile("" : "+v"(wn[s]));
    }

    const float* Fb = F + (size_t)(b * 64 + c0) * HW;
    float* ab = accp + (size_t)(b * 64 + c0) * HW + h * W + w;

    const bool interior = (bx >= 1) && (bx <= 8);
    int colidx[12];
    if (!interior) {
        #pragma unroll
        for (int j = 0; j < 12; ++j) {
            int x = w - 4 + j;
            if (x < 0) x = -x;
            if (x >= W) x = 2 * W - 2 - x;
            colidx[j] = x;
        }
    }

    #pragma unroll 1
    for (int oct = 0; oct < 2; ++oct) {
        const float* cb0 = Fb + (size_t)(oct * 8) * HW;
        f4 acc[8];
        #pragma unroll
        for (int i = 0; i < 8; ++i) acc[i] = (f4){0.f, 0.f, 0.f, 0.f};

        if (interior) {
            #pragma unroll
            for (int r = 0; r < 5; ++r) {
                const int rbase = rowoff[r] + w - 4;
                #pragma unroll
                for (int i = 0; i < 8; ++i) {
                    const float* cb = cb0 + (size_t)i * HW + rbase;
                    const f4 a0 = *(const f4*)(cb);
                    const f4 a1 = *(const f4*)(cb + 4);
                    const f4 a2 = *(const f4*)(cb + 8);
                    if ((r & 1) == 0) {            // wide taps dy={-4,0,4}
                        const int sy = r >> 1;
                        acc[i] += wb[sy * 3 + 0] * a0;
                        acc[i] += wb[sy * 3 + 1] * a1;
                        acc[i] += wb[sy * 3 + 2] * a2;
                    }
                    if (r >= 1 && r <= 3) {        // narrow taps dy={-2,0,2}
                        const int sy = r - 1;
                        const f4 m0v = __builtin_shufflevector(a0, a1, 2, 3, 4, 5);
                        const f4 m2v = __builtin_shufflevector(a1, a2, 2, 3, 4, 5);
                        acc[i] += wn[sy * 3 + 0] * m0v;
                        acc[i] += wn[sy * 3 + 1] * a1;
                        acc[i] += wn[sy * 3 + 2] * m2v;
                    }
                }
            }
        } else {
            #pragma unroll
            for (int r = 0; r < 5; ++r) {
                #pragma unroll
                for (int i = 0; i < 8; ++i) {
                    const float* cb = cb0 + (size_t)i * HW + rowoff[r];
                    float e[12];
                    #pragma unroll
                    for (int j = 0; j < 12; ++j) e[j] = cb[colidx[j]];
                    if ((r & 1) == 0) {
                        const int sy = r >> 1;
                        #pragma unroll
                        for (int sx = 0; sx < 3; ++sx)
                            #pragma unroll
                            for (int p = 0; p < 4; ++p)
                                acc[i][p] += wb[sy * 3 + sx][p] * e[4 * sx + p];
                    }
                    if (r >= 1 && r <= 3) {
                        const int sy = r - 1;
                        #pragma unroll
                        for (int sx = 0; sx < 3; ++sx)
                            #pragma unroll
                            for (int p = 0; p < 4; ++p)
                                acc[i][p] += wn[sy * 3 + sx][p] * e[2 + 2 * sx + p];
                    }
                }
            }
        }

        f4 gs = {0.f, 0.f, 0.f, 0.f};
        #pragma unroll
        for (int i = 0; i < 8; ++i) {
            __builtin_nontemporal_store(acc[i], (f4*)(ab + (size_t)(oct * 8 + i) * HW));
            gs += acc[i];
        }
        if (WRITE_GSUM) {
            const int g = quad * 2 + oct;          // full group sum in-thread
            *(f4*)(gsum + (size_t)(b * 8 + g) * HW + h * W + w) = gs * 0.125f;
        }
    }
}

__device__ __forceinline__ void mlp4(
    const f4* xs,
    const float* __restrict__ w0, const float* __restrict__ b0,
    const float* __restrict__ g0, const float* __restrict__ beta0,
    const float* __restrict__ m0, const float* __restrict__ v0,
    const float* __restrict__ w1, const float* __restrict__ b1,
    const float* __restrict__ g1, const float* __restrict__ beta1,
    const float* __restrict__ m1, const float* __restrict__ v1,
    const float* __restrict__ ws, const float* __restrict__ bs,
    f4& sv)
{
    #pragma unroll
    for (int p = 0; p < 4; ++p) {
        float y0[16];
        #pragma unroll
        for (int o = 0; o < 16; ++o) {
            const float s0 = g0[o] * rsqrtf(v0[o] + EPSV);
            float z = 0.f;
            #pragma unroll
            for (int i = 0; i < 8; ++i) z += w0[o * 8 + i] * xs[i][p];
            z = z * s0 + (b0[o] - m0[o]) * s0 + beta0[o];
            y0[o] = fmaxf(z, 0.f);
        }
        float y1[8];
        #pragma unroll
        for (int o = 0; o < 8; ++o) {
            const float s1 = g1[o] * rsqrtf(v1[o] + EPSV);
            float z = 0.f;
            #pragma unroll
            for (int i = 0; i < 16; ++i) z += w1[o * 16 + i] * y0[i];
            z = z * s1 + (b1[o] - m1[o]) * s1 + beta1[o];
            y1[o] = fmaxf(z, 0.f);
        }
        float sm = bs[0];
        #pragma unroll
        for (int i = 0; i < 8; ++i) sm += ws[i] * y1[i];
        sv[p] = 1.f / (1.f + __expf(-sm));
    }
}

__global__ __launch_bounds__(256) void fwn_head(
    const float* __restrict__ gsum,
    const float* __restrict__ w0, const float* __restrict__ b0,
    const float* __restrict__ g0, const float* __restrict__ beta0,
    const float* __restrict__ m0, const float* __restrict__ v0,
    const float* __restrict__ w1, const float* __restrict__ b1,
    const float* __restrict__ g1, const float* __restrict__ beta1,
    const float* __restrict__ m1, const float* __restrict__ v1,
    const float* __restrict__ ws, const float* __restrict__ bs,
    float* __restrict__ sig, int HW)
{
    const int jq = blockIdx.x * 256 + threadIdx.x;
    const int qHW = HW >> 2;
    const int b = jq / qHW;
    const int pq = jq - b * qHW;
    const float* gp = gsum + (size_t)b * 8 * HW + pq * 4;
    f4 xs[8];
    #pragma unroll
    for (int g = 0; g < 8; ++g) xs[g] = *(const f4*)(gp + (size_t)g * HW);
    f4 sv;
    mlp4(xs, w0, b0, g0, beta0, m0, v0, w1, b1, g1, beta1, m1, v1, ws, bs, sv);
    *(f4*)(sig + (size_t)b * HW + pq * 4) = sv;
}

__global__ __launch_bounds__(256) void fwn_head_acc(
    const float* __restrict__ accp,
    const float* __restrict__ w0, const float* __restrict__ b0,
    const float* __restrict__ g0, const float* __restrict__ beta0,
    const float* __restrict__ m0, const float* __restrict__ v0,
    const float* __restrict__ w1, const float* __restrict__ b1,
    const float* __restrict__ g1, const float* __restrict__ beta1,
    const float* __restrict__ m1, const float* __restrict__ v1,
    const float* __restrict__ ws, const float* __restrict__ bs,
    float* __restrict__ sig, int HW)
{
    const int jq = blockIdx.x * 256 + threadIdx.x;
    const int qHW = HW >> 2;
    const int b = jq / qHW;
    const int pq = jq - b * qHW;
    const float* ap = accp + (size_t)b * 64 * HW + pq * 4;
    f4 xs[8];
    #pragma unroll
    for (int g = 0; g < 8; ++g) {
        f4 t = (f4){0.f, 0.f, 0.f, 0.f};
        #pragma unroll
        for (int c = 0; c < 8; ++c)
            t += *(const f4*)(ap + (size_t)(g * 8 + c) * HW);
        xs[g] = t * 0.125f;
    }
    f4 sv;
    mlp4(xs, w0, b0, g0, beta0, m0, v0, w1, b1, g1, beta1, m1, v1, ws, bs, sv);
    *(f4*)(sig + (size_t)b * HW + pq * 4) = sv;
}

extern "C" void kernel_launch(void* const* d_in, const int* in_sizes, int n_in,
                              void* d_out, int out_size, void* d_ws, size_t ws_size,
                              hipStream_t stream) {
    const float* F    = (const float*)d_in[0];
    const float* off  = (const float*)d_in[1];
    const float* w0   = (const float*)d_in[2];
    const float* b0   = (const float*)d_in[3];
    const float* g0   = (const float*)d_in[4];
    const float* bt0  = (const float*)d_in[5];
    const float* m0   = (const float*)d_in[6];
    const float* v0   = (const float*)d_in[7];
    const float* w1   = (const float*)d_in[8];
    const float* b1   = (const float*)d_in[9];
    const float* g1   = (const float*)d_in[10];
    const float* bt1  = (const float*)d_in[11];
    const float* m1   = (const float*)d_in[12];
    const float* v1   = (const float*)d_in[13];
    const float* ws   = (const float*)d_in[14];
    const float* bs   = (const float*)d_in[15];

    const int B = 2, H = 512, W = 640;
    const int HW = H * W;
    float* sig  = (float*)d_out;                  // [B,H,W]
    float* accp = sig + (size_t)B * HW;           // [B,64,H,W]
    float* gsum = (float*)d_ws;                   // [B,8,H,W] = 20.97 MB

    const size_t gsum_bytes = (size_t)B * 8 * HW * sizeof(float);
    const int use_ws = (ws_size >= gsum_bytes) ? 1 : 0;
    const int nq = (B * HW) / 4;                  // 163840 -> 640 blocks

    if (use_ws) {
        fwn_stencil<true><<<dim3(2560), dim3(256), 0, stream>>>(
            F, off, accp, gsum, H, W);
        fwn_head<<<dim3(nq / 256), dim3(256), 0, stream>>>(
            gsum, w0, b0, g0, bt0, m0, v0, w1, b1, g1, bt1, m1, v1, ws, bs,
            sig, HW);
    } else {
        fwn_stencil<false><<<dim3(2560), dim3(256), 0, stream>>>(
            F, off, accp, gsum, H, W);
        fwn_head_acc<<<dim3(nq / 256), dim3(256), 0, stream>>>(
            accp, w0, b0, g0, bt0, m0, v0, w1, b1, g1, bt1, m1, v1, ws, bs,
            sig, HW);
    }
}

// Round 9
// 113.356 us; speedup vs baseline: 2.7528x; 2.7528x over previous
//
#include <hip/hip_runtime.h>
#include <math.h>

// FeatureWeightNet v9 (MI355X / gfx950)  B=2, C=64, H=512, W=640.
// Pipelined LDS-staged stencil.
//   Block = 64x16 px tile x 32 ch (8 passes x 4 ch). Grid = 1280 blocks.
//   Staging via __builtin_amdgcn_global_load_lds (16B, zero dest VGPRs) into
//   DOUBLE-BUFFERED slabs [4][24][80] f32 (2x30720B = 61440B LDS).
//   Pipeline: pass k computes buf[k&1] while stage(k+1) is in flight;
//   stage(k+2) issues after the post-compute barrier. Counted
//   s_waitcnt vmcnt(8/7) + raw s_barrier (NOT __syncthreads -> no vmcnt(0)
//   drain). Weights: 18 f4 pinned in VGPRs (no remat; staging needs no regs
//   so the 72-reg cost doesn't starve MLP like R8).
//   Border-x blocks (bx 0,9; 20%): sync reg-gather path with reflection.
// Head: 8->16->8->1 MLP + sigmoid from gsum[B,8,H,W] (d_ws), acc fallback.

typedef float f4 __attribute__((ext_vector_type(4)));
#define EPSV 1e-5f
#define CPP 4          // channels per pass
#define LWF 80         // slab row width (floats): 64 + 2*4 halo, pad to 80
#define LHH 24         // slab rows: 16 + 2*4 halo
#define NF4 1920       // CPP*LHH*LWF/4 f4 per slab; 1920 = 30 wave-chunks

__device__ __forceinline__ void gload_lds16(const float* g, float* l) {
    auto gp = (const __attribute__((address_space(1))) float*)g;
    auto lp = (__attribute__((address_space(3))) float*)l;
    __builtin_amdgcn_global_load_lds(gp, lp, 16, 0, 0);
}

// one pass = 4 channels from an LDS slab; acc NT-stored; group-sum carried
__device__ __forceinline__ void compute_pass(
    const float* lbuf, int kk, int ry, int qx,
    const f4* wb, const f4* wn,
    float* ab, float* gp0, f4& gs, int HW, int wg)
{
    f4 acc[CPP];
    #pragma unroll
    for (int i = 0; i < CPP; ++i) acc[i] = (f4){0.f, 0.f, 0.f, 0.f};
    #pragma unroll
    for (int r = 0; r < 5; ++r) {            // tap rows dy = {-4,-2,0,2,4}
        #pragma unroll
        for (int i = 0; i < CPP; ++i) {
            const float* lp = lbuf + ((i * LHH + (ry + 2 * r)) * LWF + qx * 4);
            const f4 a0 = *(const f4*)(lp);
            const f4 a1 = *(const f4*)(lp + 4);
            const f4 a2 = *(const f4*)(lp + 8);
            if ((r & 1) == 0) {              // wide taps {-4,0,4}
                const int sy = r >> 1;
                acc[i] += wb[sy * 3 + 0] * a0;
                acc[i] += wb[sy * 3 + 1] * a1;
                acc[i] += wb[sy * 3 + 2] * a2;
            }
            if (r >= 1 && r <= 3) {          // narrow taps {-2,0,2}
                const int sy = r - 1;
                const f4 m0v = __builtin_shufflevector(a0, a1, 2, 3, 4, 5);
                const f4 m2v = __builtin_shufflevector(a1, a2, 2, 3, 4, 5);
                acc[i] += wn[sy * 3 + 0] * m0v;
                acc[i] += wn[sy * 3 + 1] * a1;
                acc[i] += wn[sy * 3 + 2] * m2v;
            }
        }
    }
    #pragma unroll
    for (int i = 0; i < CPP; ++i) {
        __builtin_nontemporal_store(acc[i], (f4*)(ab + (size_t)(kk * CPP + i) * HW));
        gs += acc[i];
    }
    if (kk & 1) {                            // full 8-ch group done
        if (wg) *(f4*)(gp0 + (size_t)(kk >> 1) * HW) = gs * 0.125f;
        gs = (f4){0.f, 0.f, 0.f, 0.f};
    }
}

__global__ __launch_bounds__(256, 2) void fwn_stencil(
    const float* __restrict__ F,    // [B,64,H,W]
    const float* __restrict__ off,  // [B,18,H,W]
    float* __restrict__ accp,       // [B,64,H,W]
    float* __restrict__ gsum,       // [B,8,H,W]
    int H, int W, int wg)
{
    const int HW = H * W;
    __shared__ float lds[2][NF4 * 4];        // 61440 B

    // 1280 blocks = 8 XCDs * 160; chhalf innermost, then y, then strip.
    const int f = blockIdx.x;
    const int l = (f & 7) * 160 + (f >> 3);
    const int chhalf = l & 1;
    const int by     = (l >> 1) & 31;
    const int strip  = l >> 6;               // 0..19
    const int bx = strip % 10;
    const int b  = strip / 10;

    const int tid = threadIdx.x;
    const int qx = tid & 15;
    const int ry = tid >> 4;                 // 0..15
    const int x0 = bx * 64;
    const int h0 = by * 16;
    const int w = x0 + qx * 4;
    const int h = h0 + ry;
    const int cbase = chhalf * 32;

    // ---- 18 per-pixel weight f4s, pre-scaled 0.5, loaded once, pinned ----
    const float* op = off + (size_t)b * 18 * HW + h * W + w;
    f4 wb[9], wn[9];
    #pragma unroll
    for (int s = 0; s < 9; ++s) {
        wb[s] = 0.5f * *(const f4*)(op + (size_t)s * HW);
        wn[s] = 0.5f * *(const f4*)(op + (size_t)(s + 9) * HW);
    }
    #pragma unroll
    for (int s = 0; s < 9; ++s) {
        asm volatile("" : "+v"(wb[s]));
        asm volatile("" : "+v"(wn[s]));
    }

    const float* Fb = F + (size_t)(b * 64 + cbase) * HW;
    float* ab  = accp + (size_t)(b * 64 + cbase) * HW + h * W + w;
    float* gp0 = gsum + (size_t)(b * 8 + chhalf * 4) * HW + h * W + w;
    f4 gs = {0.f, 0.f, 0.f, 0.f};

    if (bx >= 1 && bx <= 8) {
        // =============== interior: async pipelined staging ===============
        // per-chunk source element offsets (pass-invariant; row-reflected)
        int choff[8];
        #pragma unroll
        for (int p = 0; p < 8; ++p) {
            const int j   = p * 256 + tid;
            const int ch  = j / 480;         // 480 = LHH*LWF/4
            const int rem = j - ch * 480;
            const int row = rem / 20;        // 20 = LWF/4
            const int c4  = rem - row * 20;
            int ar = h0 - 4 + row;
            if (ar < 0) ar = -ar;
            if (ar >= H) ar = 2 * H - 2 - ar;
            choff[p] = ch * HW + ar * W + (x0 - 4) + c4 * 4;
        }

#define STAGE(S, BUF) do {                                                    \
        const float* Fp_ = Fb + (size_t)((S) * CPP) * HW;                     \
        _Pragma("unroll")                                                     \
        for (int p = 0; p < 8; ++p) {                                         \
            if (p * 256 + tid < NF4)                                          \
                gload_lds16(Fp_ + choff[p],                                   \
                            &lds[BUF][(p * 256 + (tid >> 6) * 64) * 4]);      \
        } } while (0)

#define WAIT_STAGE() do {                                                     \
        if (tid < 128) asm volatile("s_waitcnt vmcnt(8)" ::: "memory");       \
        else           asm volatile("s_waitcnt vmcnt(7)" ::: "memory");       \
        } while (0)

#define BARRIER() do {                                                        \
        asm volatile("" ::: "memory");                                        \
        __builtin_amdgcn_s_barrier();                                         \
        asm volatile("" ::: "memory"); } while (0)

#define PASS(K) do {                                                          \
        WAIT_STAGE();                                                         \
        BARRIER();                                                            \
        compute_pass(&lds[(K) & 1][0], K, ry, qx, wb, wn, ab, gp0, gs, HW, wg);\
        BARRIER();                                                            \
        if ((K) + 2 < 8) STAGE((K) + 2, (K) & 1);                             \
        } while (0)

        STAGE(0, 0);
        STAGE(1, 1);
        PASS(0); PASS(1); PASS(2); PASS(3); PASS(4); PASS(5); PASS(6);
        // pass 7: nothing younger but stores(6) -> full drain is fine
        asm volatile("s_waitcnt vmcnt(0)" ::: "memory");
        BARRIER();
        compute_pass(&lds[7 & 1][0], 7, ry, qx, wb, wn, ab, gp0, gs, HW, wg);
    } else {
        // =============== border-x: sync reg-gather staging ===============
        #pragma unroll 1
        for (int k = 0; k < 8; ++k) {
            const float* Fp = Fb + (size_t)(k * CPP) * HW;
            f4 v[8];
            #pragma unroll
            for (int p = 0; p < 8; ++p) {
                const int j = p * 256 + tid;
                if (j < NF4) {
                    const int ch  = j / 480;
                    const int rem = j - ch * 480;
                    const int row = rem / 20;
                    const int c4  = rem - row * 20;
                    int ar = h0 - 4 + row;
                    if (ar < 0) ar = -ar;
                    if (ar >= H) ar = 2 * H - 2 - ar;
                    const float* src = Fp + (size_t)ch * HW + ar * W;
                    #pragma unroll
                    for (int m = 0; m < 4; ++m) {
                        int x = x0 - 4 + c4 * 4 + m;
                        if (x < 0) x = -x;
                        if (x >= W) x = 2 * W - 2 - x;
                        v[p][m] = src[x];
                    }
                }
            }
            __syncthreads();                 // prior compute done reading
            #pragma unroll
            for (int p = 0; p < 8; ++p) {
                const int j = p * 256 + tid;
                if (j < NF4) *(f4*)&lds[0][j * 4] = v[p];
            }
            __syncthreads();
            compute_pass(&lds[0][0], k, ry, qx, wb, wn, ab, gp0, gs, HW, wg);
        }
    }
}

__device__ __forceinline__ void mlp4(
    const f4* xs,
    const float* __restrict__ w0, const float* __restrict__ b0,
    const float* __restrict__ g0, const float* __restrict__ beta0,
    const float* __restrict__ m0, const float* __restrict__ v0,
    const float* __restrict__ w1, const float* __restrict__ b1,
    const float* __restrict__ g1, const float* __restrict__ beta1,
    const float* __restrict__ m1, const float* __restrict__ v1,
    const float* __restrict__ ws, const float* __restrict__ bs,
    f4& sv)
{
    #pragma unroll
    for (int p = 0; p < 4; ++p) {
        float y0[16];
        #pragma unroll
        for (int o = 0; o < 16; ++o) {
            const float s0 = g0[o] * rsqrtf(v0[o] + EPSV);
            float z = 0.f;
            #pragma unroll
            for (int i = 0; i < 8; ++i) z += w0[o * 8 + i] * xs[i][p];
            z = z * s0 + (b0[o] - m0[o]) * s0 + beta0[o];
            y0[o] = fmaxf(z, 0.f);
        }
        float y1[8];
        #pragma unroll
        for (int o = 0; o < 8; ++o) {
            const float s1 = g1[o] * rsqrtf(v1[o] + EPSV);
            float z = 0.f;
            #pragma unroll
            for (int i = 0; i < 16; ++i) z += w1[o * 16 + i] * y0[i];
            z = z * s1 + (b1[o] - m1[o]) * s1 + beta1[o];
            y1[o] = fmaxf(z, 0.f);
        }
        float sm = bs[0];
        #pragma unroll
        for (int i = 0; i < 8; ++i) sm += ws[i] * y1[i];
        sv[p] = 1.f / (1.f + __expf(-sm));
    }
}

__global__ __launch_bounds__(256) void fwn_head(
    const float* __restrict__ gsum,
    const float* __restrict__ w0, const float* __restrict__ b0,
    const float* __restrict__ g0, const float* __restrict__ beta0,
    const float* __restrict__ m0, const float* __restrict__ v0,
    const float* __restrict__ w1, const float* __restrict__ b1,
    const float* __restrict__ g1, const float* __restrict__ beta1,
    const float* __restrict__ m1, const float* __restrict__ v1,
    const float* __restrict__ ws, const float* __restrict__ bs,
    float* __restrict__ sig, int HW)
{
    const int jq = blockIdx.x * 256 + threadIdx.x;
    const int qHW = HW >> 2;
    const int b = jq / qHW;
    const int pq = jq - b * qHW;
    const float* gp = gsum + (size_t)b * 8 * HW + pq * 4;
    f4 xs[8];
    #pragma unroll
    for (int g = 0; g < 8; ++g) xs[g] = *(const f4*)(gp + (size_t)g * HW);
    f4 sv;
    mlp4(xs, w0, b0, g0, beta0, m0, v0, w1, b1, g1, beta1, m1, v1, ws, bs, sv);
    *(f4*)(sig + (size_t)b * HW + pq * 4) = sv;
}

__global__ __launch_bounds__(256) void fwn_head_acc(
    const float* __restrict__ accp,
    const float* __restrict__ w0, const float* __restrict__ b0,
    const float* __restrict__ g0, const float* __restrict__ beta0,
    const float* __restrict__ m0, const float* __restrict__ v0,
    const float* __restrict__ w1, const float* __restrict__ b1,
    const float* __restrict__ g1, const float* __restrict__ beta1,
    const float* __restrict__ m1, const float* __restrict__ v1,
    const float* __restrict__ ws, const float* __restrict__ bs,
    float* __restrict__ sig, int HW)
{
    const int jq = blockIdx.x * 256 + threadIdx.x;
    const int qHW = HW >> 2;
    const int b = jq / qHW;
    const int pq = jq - b * qHW;
    const float* ap = accp + (size_t)b * 64 * HW + pq * 4;
    f4 xs[8];
    #pragma unroll
    for (int g = 0; g < 8; ++g) {
        f4 t = (f4){0.f, 0.f, 0.f, 0.f};
        #pragma unroll
        for (int c = 0; c < 8; ++c)
            t += *(const f4*)(ap + (size_t)(g * 8 + c) * HW);
        xs[g] = t * 0.125f;
    }
    f4 sv;
    mlp4(xs, w0, b0, g0, beta0, m0, v0, w1, b1, g1, beta1, m1, v1, ws, bs, sv);
    *(f4*)(sig + (size_t)b * HW + pq * 4) = sv;
}

extern "C" void kernel_launch(void* const* d_in, const int* in_sizes, int n_in,
                              void* d_out, int out_size, void* d_ws, size_t ws_size,
                              hipStream_t stream) {
    const float* F    = (const float*)d_in[0];
    const float* off  = (const float*)d_in[1];
    const float* w0   = (const float*)d_in[2];
    const float* b0   = (const float*)d_in[3];
    const float* g0   = (const float*)d_in[4];
    const float* bt0  = (const float*)d_in[5];
    const float* m0   = (const float*)d_in[6];
    const float* v0   = (const float*)d_in[7];
    const float* w1   = (const float*)d_in[8];
    const float* b1   = (const float*)d_in[9];
    const float* g1   = (const float*)d_in[10];
    const float* bt1  = (const float*)d_in[11];
    const float* m1   = (const float*)d_in[12];
    const float* v1   = (const float*)d_in[13];
    const float* ws   = (const float*)d_in[14];
    const float* bs   = (const float*)d_in[15];

    const int B = 2, H = 512, W = 640;
    const int HW = H * W;
    float* sig  = (float*)d_out;                  // [B,H,W]
    float* accp = sig + (size_t)B * HW;           // [B,64,H,W]
    float* gsum = (float*)d_ws;                   // [B,8,H,W] = 20.97 MB

    const size_t gsum_bytes = (size_t)B * 8 * HW * sizeof(float);
    const int use_ws = (ws_size >= gsum_bytes) ? 1 : 0;
    const int nq = (B * HW) / 4;                  // 163840 -> 640 blocks

    fwn_stencil<<<dim3(1280), dim3(256), 0, stream>>>(
        F, off, accp, gsum, H, W, use_ws);
    if (use_ws) {
        fwn_head<<<dim3(nq / 256), dim3(256), 0, stream>>>(
            gsum, w0, b0, g0, bt0, m0, v0, w1, b1, g1, bt1, m1, v1, ws, bs,
            sig, HW);
    } else {
        fwn_head_acc<<<dim3(nq / 256), dim3(256), 0, stream>>>(
            accp, w0, b0, g0, bt0, m0, v0, w1, b1, g1, bt1, m1, v1, ws, bs,
            sig, HW);
    }
}